// Round 3
// baseline (1443.402 us; speedup 1.0000x reference)
//
#include <hip/hip_runtime.h>

typedef unsigned long long u64;
typedef unsigned int u32;

#define TBL_BITS 18
#define TBL_SIZE (1u << TBL_BITS)
#define TBL_MASK (TBL_SIZE - 1u)
#define EMPTY_KEY 0xFFFFFFFFFFFFFFFFull

__device__ __forceinline__ u64 splitmix64(u64 z) {
    z = z + 0x9E3779B97F4A7C15ull;
    z = (z ^ (z >> 30)) * 0xBF58476D1CE4E5B9ull;
    z = (z ^ (z >> 27)) * 0x94D049BB133111EBull;
    return z ^ (z >> 31);
}

// colors0 = argmax over 64 features per node; one 64-lane wave per row.
__global__ void argmax_kernel(const float* __restrict__ x, u32* __restrict__ colors,
                              int* __restrict__ out, u32* __restrict__ offsets, int n) {
    if (blockIdx.x == 0 && threadIdx.x == 0) offsets[0] = 0u;
    int wave = (int)((blockIdx.x * (u32)blockDim.x + threadIdx.x) >> 6);
    int lane = threadIdx.x & 63;
    if (wave >= n) return;
    float v = x[(size_t)wave * 64 + lane];
    int idx = lane;
    #pragma unroll
    for (int off = 32; off >= 1; off >>= 1) {
        float ov = __shfl_xor(v, off);
        int   oi = __shfl_xor(idx, off);
        if (ov > v || (ov == v && oi < idx)) { v = ov; idx = oi; }
    }
    if (lane == 0) {
        colors[wave] = (u32)idx;
        out[(size_t)wave * 4 + 0] = idx;
    }
}

// Per-iteration init: clear hash table; compute h = splitmix64(color+1); zero nb_sum.
__global__ void init_iter_kernel(u64* __restrict__ keys, u32* __restrict__ vals,
                                 const u32* __restrict__ colors,
                                 u64* __restrict__ h, u64* __restrict__ nb, int n) {
    int i = blockIdx.x * blockDim.x + threadIdx.x;
    if (i < (int)TBL_SIZE) { keys[i] = EMPTY_KEY; vals[i] = 0xFFFFFFFFu; }
    if (i < n) { h[i] = splitmix64((u64)colors[i] + 1ull); nb[i] = 0ull; }
}

// Scatter-add neighbor hashes: nb[dst] += h[src].  u64 wrap-around add is
// commutative/associative -> atomic order doesn't affect the result.
__global__ void edge_kernel(const int* __restrict__ src, const int* __restrict__ dst,
                            const u64* __restrict__ h, u64* __restrict__ nb, int m) {
    int stride = gridDim.x * blockDim.x;
    for (int e = blockIdx.x * blockDim.x + threadIdx.x; e < m; e += stride) {
        atomicAdd(&nb[(u32)dst[e]], h[(u32)src[e]]);
    }
}

// sig = splitmix64(h*FNV + nb); insert into hash table, tracking min node index
// per signature (first occurrence).
__global__ void sig_kernel(const u64* __restrict__ h, const u64* __restrict__ nb,
                           u64* __restrict__ sig, u64* __restrict__ keys,
                           u32* __restrict__ vals, int n) {
    int i = blockIdx.x * blockDim.x + threadIdx.x;
    if (i >= n) return;
    u64 s = splitmix64(h[i] * 0x100000001B3ull + nb[i]);
    sig[i] = s;
    u32 slot = (u32)s & TBL_MASK;
    while (true) {
        u64 prev = atomicCAS(&keys[slot], (u64)EMPTY_KEY, s);
        if (prev == EMPTY_KEY || prev == s) break;
        slot = (slot + 1u) & TBL_MASK;
    }
    atomicMin(&vals[slot], (u32)i);
}

// f[i] = first-occurrence node index of sig[i].
__global__ void lookup_kernel(const u64* __restrict__ sig, const u64* __restrict__ keys,
                              const u32* __restrict__ vals, u32* __restrict__ f, int n) {
    int i = blockIdx.x * blockDim.x + threadIdx.x;
    if (i >= n) return;
    u64 s = sig[i];
    u32 slot = (u32)s & TBL_MASK;
    while (keys[slot] != s) slot = (slot + 1u) & TBL_MASK;
    f[i] = vals[slot];
}

// Single-block exclusive scan of is_first predicate -> rank array; also
// advances the persistent color counter: offsets[it+1] = offsets[it] + #new.
__global__ void scan_kernel(const u32* __restrict__ f, u32* __restrict__ rank,
                            u32* __restrict__ offsets, int iter, int n) {
    __shared__ u32 bufA[1024], bufB[1024];
    int tid = threadIdx.x;
    int chunk = (n + 1023) >> 10;
    int begin = tid * chunk;
    int end = begin + chunk; if (end > n) end = n; if (begin > n) begin = n;
    u32 s = 0;
    for (int i = begin; i < end; ++i) s += (f[i] == (u32)i) ? 1u : 0u;
    bufA[tid] = s;
    __syncthreads();
    u32* cur = bufA; u32* nxt = bufB;
    for (int off = 1; off < 1024; off <<= 1) {
        u32 v = cur[tid] + ((tid >= off) ? cur[tid - off] : 0u);
        nxt[tid] = v;
        __syncthreads();
        u32* t = cur; cur = nxt; nxt = t;
    }
    u32 excl = cur[tid] - s;  // exclusive prefix of this thread's chunk
    u32 running = excl;
    for (int i = begin; i < end; ++i) {
        rank[i] = running;
        running += (f[i] == (u32)i) ? 1u : 0u;
    }
    if (tid == 1023) offsets[iter + 1] = offsets[iter] + cur[1023];
}

// new_color = offset_old + rank_of_first_occurrence; emit output column (int32).
__global__ void relabel_kernel(const u32* __restrict__ f, const u32* __restrict__ rank,
                               const u32* __restrict__ offsets, int iter,
                               u32* __restrict__ colors, int* __restrict__ out, int n) {
    int i = blockIdx.x * blockDim.x + threadIdx.x;
    if (i >= n) return;
    u32 c = offsets[iter] + rank[f[i]];
    colors[i] = c;
    out[(size_t)i * 4 + (iter + 1)] = (int)c;
}

extern "C" void kernel_launch(void* const* d_in, const int* in_sizes, int n_in,
                              void* d_out, int out_size, void* d_ws, size_t ws_size,
                              hipStream_t stream) {
    const float* x = (const float*)d_in[0];
    const int* ei = (const int*)d_in[1];     // integer inputs are int32 on device
    int n = in_sizes[0] / 64;                // 100000 nodes
    int m = in_sizes[1] / 2;                 // 6.4M edges
    const int* src = ei;
    const int* dst = ei + m;
    int* out = (int*)d_out;                  // integer reference output -> int32 buffer

    char* p = (char*)d_ws;
    u64* h       = (u64*)p; p += (size_t)n * 8;
    u64* nb      = (u64*)p; p += (size_t)n * 8;
    u64* sig     = (u64*)p; p += (size_t)n * 8;
    u64* keys    = (u64*)p; p += (size_t)TBL_SIZE * 8;
    u32* vals    = (u32*)p; p += (size_t)TBL_SIZE * 4;
    u32* f       = (u32*)p; p += (size_t)n * 4;
    u32* rank    = (u32*)p; p += (size_t)n * 4;
    u32* colors  = (u32*)p; p += (size_t)n * 4;
    u32* offsets = (u32*)p; p += 16;

    argmax_kernel<<<(n + 3) / 4, 256, 0, stream>>>(x, colors, out, offsets, n);

    for (int it = 0; it < 3; ++it) {
        init_iter_kernel<<<(TBL_SIZE + 255) / 256, 256, 0, stream>>>(keys, vals, colors, h, nb, n);
        edge_kernel<<<4096, 256, 0, stream>>>(src, dst, h, nb, m);
        sig_kernel<<<(n + 255) / 256, 256, 0, stream>>>(h, nb, sig, keys, vals, n);
        lookup_kernel<<<(n + 255) / 256, 256, 0, stream>>>(sig, keys, vals, f, n);
        scan_kernel<<<1, 1024, 0, stream>>>(f, rank, offsets, it, n);
        relabel_kernel<<<(n + 255) / 256, 256, 0, stream>>>(f, rank, offsets, it, colors, out, n);
    }
}

// Round 4
// 308.057 us; speedup vs baseline: 4.6855x; 4.6855x over previous
//
#include <hip/hip_runtime.h>

typedef unsigned long long u64;
typedef unsigned int u32;

#define TBL_BITS 18
#define TBL_SIZE (1u << TBL_BITS)
#define TBL_MASK (TBL_SIZE - 1u)
#define EMPTY_KEY 0xFFFFFFFFFFFFFFFFull

#define NB   196    // node buckets of 512: ceil(100000/512)
#define NBLK 128    // partition blocks
#define CNT_ENTRIES (NB * NBLK)

__device__ __forceinline__ u64 splitmix64(u64 z) {
    z = z + 0x9E3779B97F4A7C15ull;
    z = (z ^ (z >> 30)) * 0xBF58476D1CE4E5B9ull;
    z = (z ^ (z >> 27)) * 0x94D049BB133111EBull;
    return z ^ (z >> 31);
}

// ---------------- shared by both paths ----------------

// colors0 = argmax over 64 features per node (one wave per row); writes output
// column 0, h = splitmix64(color+1), and offsets[0] = 0.
__global__ void argmax_kernel(const float* __restrict__ x, u64* __restrict__ h,
                              int* __restrict__ out, u32* __restrict__ offsets, int n) {
    if (blockIdx.x == 0 && threadIdx.x == 0) offsets[0] = 0u;
    int wave = (int)((blockIdx.x * (u32)blockDim.x + threadIdx.x) >> 6);
    int lane = threadIdx.x & 63;
    if (wave >= n) return;
    float v = x[(size_t)wave * 64 + lane];
    int idx = lane;
    #pragma unroll
    for (int off = 32; off >= 1; off >>= 1) {
        float ov = __shfl_xor(v, off);
        int   oi = __shfl_xor(idx, off);
        if (ov > v || (ov == v && oi < idx)) { v = ov; idx = oi; }
    }
    if (lane == 0) {
        h[wave] = splitmix64((u64)idx + 1ull);
        out[(size_t)wave * 4 + 0] = idx;
    }
}

// sig = splitmix64(h*FNV + nb); insert into hash table; first occurrence via
// atomicMin (order-independent).
__global__ void sig_kernel(const u64* __restrict__ h, const u64* __restrict__ nb,
                           u64* __restrict__ sig, u64* __restrict__ keys,
                           u32* __restrict__ vals, int n) {
    int i = blockIdx.x * blockDim.x + threadIdx.x;
    if (i >= n) return;
    u64 s = splitmix64(h[i] * 0x100000001B3ull + nb[i]);
    sig[i] = s;
    u32 slot = (u32)s & TBL_MASK;
    while (true) {
        u64 prev = atomicCAS(&keys[slot], (u64)EMPTY_KEY, s);
        if (prev == EMPTY_KEY || prev == s) break;
        slot = (slot + 1u) & TBL_MASK;
    }
    atomicMin(&vals[slot], (u32)i);
}

// ---------------- fast path ----------------

// Per-block LDS histogram of dst buckets -> cnt[bucket*NBLK + blk].
__global__ __launch_bounds__(1024) void count_part(const int* __restrict__ dst,
                                                   u32* __restrict__ cnt, int m) {
    __shared__ u32 hist[NB];
    int t = threadIdx.x, b = blockIdx.x;
    if (t < NB) hist[t] = 0u;
    __syncthreads();
    int per = (m + NBLK - 1) / NBLK;
    int lo = b * per, hi = lo + per; if (hi > m) hi = m;
    for (int e = lo + t; e < hi; e += 1024) atomicAdd(&hist[((u32)dst[e]) >> 9], 1u);
    __syncthreads();
    if (t < NB) cnt[t * NBLK + b] = hist[t];
}

// Flat exclusive scan over cnt (bucket-major) -> off. 1 block, 1024 threads.
__global__ __launch_bounds__(1024) void scan_flat(const u32* __restrict__ cnt,
                                                  u32* __restrict__ off) {
    __shared__ u32 A[1024], B[1024];
    int t = threadIdx.x;
    int chunk = (CNT_ENTRIES + 1023) / 1024;
    int lo = t * chunk, hi = lo + chunk;
    if (lo > CNT_ENTRIES) lo = CNT_ENTRIES;
    if (hi > CNT_ENTRIES) hi = CNT_ENTRIES;
    u32 s = 0;
    for (int i = lo; i < hi; ++i) s += cnt[i];
    A[t] = s; __syncthreads();
    u32 *cur = A, *nxt = B;
    for (int o = 1; o < 1024; o <<= 1) {
        u32 v = cur[t] + ((t >= o) ? cur[t - o] : 0u);
        nxt[t] = v; __syncthreads();
        u32* tmp = cur; cur = nxt; nxt = tmp;
    }
    u32 run = cur[t] - s;
    for (int i = lo; i < hi; ++i) { off[i] = run; run += cnt[i]; }
}

// Scatter edges into bucket-partitioned packed array: (src<<9)|(dst&511).
// Per-(bucket,block) regions are exclusive; LDS-atomic position assignment is
// order-nondeterministic but downstream sums are commutative -> output exact.
__global__ __launch_bounds__(1024) void scatter_part(const int* __restrict__ src,
                                                     const int* __restrict__ dst,
                                                     const u32* __restrict__ off,
                                                     u32* __restrict__ packed, int m) {
    __shared__ u32 pos[NB];
    int t = threadIdx.x, b = blockIdx.x;
    if (t < NB) pos[t] = off[t * NBLK + b];
    __syncthreads();
    int per = (m + NBLK - 1) / NBLK;
    int lo = b * per, hi = lo + per; if (hi > m) hi = m;
    for (int e = lo + t; e < hi; e += 1024) {
        u32 d = (u32)dst[e];
        u32 p = atomicAdd(&pos[d >> 9], 1u);
        packed[p] = ((u32)src[e] << 9) | (d & 511u);
    }
}

// Blocks [0,NB): bucketed neighbor-sum into 512 u64 LDS accumulators, plain
// coalesced store to nb. Blocks [NB, NB+256): clear the hash table.
__global__ __launch_bounds__(1024) void nb_kernel(const u32* __restrict__ packed,
                                                  const u32* __restrict__ off,
                                                  const u64* __restrict__ h,
                                                  u64* __restrict__ nb,
                                                  u64* __restrict__ keys,
                                                  u32* __restrict__ vals, int n, int m) {
    int b = blockIdx.x, t = threadIdx.x;
    if (b >= NB) {
        int j = (b - NB) * 1024 + t;
        keys[j] = EMPTY_KEY; vals[j] = 0xFFFFFFFFu;
        return;
    }
    __shared__ u64 acc[512];
    if (t < 512) acc[t] = 0ull;
    __syncthreads();
    int lo = (int)off[b * NBLK];
    int hi = (b == NB - 1) ? m : (int)off[(b + 1) * NBLK];
    for (int e = lo + t; e < hi; e += 1024) {
        u32 p = packed[e];
        atomicAdd(&acc[p & 511u], h[p >> 9]);
    }
    __syncthreads();
    int base = b * 512;
    if (t < 512 && base + t < n) nb[base + t] = acc[t];
}

// Lookup first-occurrence f[i], local (per-256-block) exclusive rank of the
// is-first predicate, and per-block totals.
__global__ void count_rank(const u64* __restrict__ sig, const u64* __restrict__ keys,
                           const u32* __restrict__ vals, u32* __restrict__ f,
                           u32* __restrict__ lrank, u32* __restrict__ partials, int n) {
    int b = blockIdx.x, t = threadIdx.x;
    int i = b * 256 + t;
    u32 isf = 0, fi = 0;
    if (i < n) {
        u64 s = sig[i];
        u32 slot = (u32)s & TBL_MASK;
        while (keys[slot] != s) slot = (slot + 1u) & TBL_MASK;
        fi = vals[slot];
        f[i] = fi;
        isf = (fi == (u32)i) ? 1u : 0u;
    }
    __shared__ u32 wsum[4];
    u32 lane = t & 63, wv = (u32)t >> 6;
    int x = (int)isf;
    #pragma unroll
    for (int o = 1; o < 64; o <<= 1) {
        int y = __shfl_up(x, o);
        if (lane >= (u32)o) x += y;
    }
    if (lane == 63) wsum[wv] = (u32)x;
    __syncthreads();
    u32 woff = 0;
    for (u32 w = 0; w < wv; ++w) woff += wsum[w];
    if (i < n) lrank[i] = woff + (u32)x - isf;
    if (t == 255) partials[b] = woff + (u32)x;
}

// Exclusive scan of the <=512 per-block totals; advance the color counter.
__global__ void scan_partials(const u32* __restrict__ partials, u32* __restrict__ pp,
                              u32* __restrict__ offsets, int iter, int nblk) {
    __shared__ u32 A[512], B[512];
    int t = threadIdx.x;
    u32 v = (t < nblk) ? partials[t] : 0u;
    A[t] = v; __syncthreads();
    u32 *cur = A, *nxt = B;
    for (int o = 1; o < 512; o <<= 1) {
        u32 y = cur[t] + ((t >= o) ? cur[t - o] : 0u);
        nxt[t] = y; __syncthreads();
        u32* tmp = cur; cur = nxt; nxt = tmp;
    }
    if (t < nblk) pp[t] = cur[t] - v;
    if (t == 511) offsets[iter + 1] = offsets[iter] + cur[511];
}

// color = offset + global rank of first occurrence; emit column + next h.
__global__ void relabel_fast(const u32* __restrict__ f, const u32* __restrict__ lrank,
                             const u32* __restrict__ pp, const u32* __restrict__ offsets,
                             int iter, u64* __restrict__ h, int* __restrict__ out, int n) {
    int i = blockIdx.x * 256 + threadIdx.x;
    if (i >= n) return;
    u32 j = f[i];
    u32 c = offsets[iter] + pp[j >> 8] + lrank[j];
    h[i] = splitmix64((u64)c + 1ull);
    out[(size_t)i * 4 + (iter + 1)] = (int)c;
}

// ---------------- fallback path (proven in round 3) ----------------

__global__ void init_iter_kernel(u64* __restrict__ keys, u32* __restrict__ vals,
                                 u64* __restrict__ nb, int n) {
    int i = blockIdx.x * blockDim.x + threadIdx.x;
    if (i < (int)TBL_SIZE) { keys[i] = EMPTY_KEY; vals[i] = 0xFFFFFFFFu; }
    if (i < n) nb[i] = 0ull;
}

__global__ void edge_kernel(const int* __restrict__ src, const int* __restrict__ dst,
                            const u64* __restrict__ h, u64* __restrict__ nb, int m) {
    int stride = gridDim.x * blockDim.x;
    for (int e = blockIdx.x * blockDim.x + threadIdx.x; e < m; e += stride) {
        atomicAdd(&nb[(u32)dst[e]], h[(u32)src[e]]);
    }
}

extern "C" void kernel_launch(void* const* d_in, const int* in_sizes, int n_in,
                              void* d_out, int out_size, void* d_ws, size_t ws_size,
                              hipStream_t stream) {
    const float* x = (const float*)d_in[0];
    const int* ei = (const int*)d_in[1];     // int32 on device
    int n = in_sizes[0] / 64;                // 100000 nodes
    int m = in_sizes[1] / 2;                 // 6.4M edges
    const int* src = ei;
    const int* dst = ei + m;
    int* out = (int*)d_out;

    const int NPB = (n + 255) / 256;         // 391 rank blocks

    // layout (256B aligned)
    auto align = [](size_t v) { return (v + 255) & ~(size_t)255; };
    size_t sz_packed = align((size_t)m * 4);
    size_t sz_cnt    = align((size_t)CNT_ENTRIES * 4);
    size_t sz_h      = align((size_t)n * 8);
    size_t sz_tblk   = align((size_t)TBL_SIZE * 8);
    size_t sz_tblv   = align((size_t)TBL_SIZE * 4);
    size_t sz_n4     = align((size_t)n * 4);
    size_t sz_small  = align((size_t)512 * 4);
    size_t need_fast = sz_packed + 2 * sz_cnt + 3 * sz_h + sz_tblk + sz_tblv
                     + 2 * sz_n4 + 2 * sz_small + 256;

    char* p = (char*)d_ws;
    if (ws_size >= need_fast) {
        u32* packed  = (u32*)p; p += sz_packed;
        u32* cnt     = (u32*)p; p += sz_cnt;
        u32* off     = (u32*)p; p += sz_cnt;
        u64* h       = (u64*)p; p += sz_h;
        u64* nb      = (u64*)p; p += sz_h;
        u64* sig     = (u64*)p; p += sz_h;
        u64* keys    = (u64*)p; p += sz_tblk;
        u32* vals    = (u32*)p; p += sz_tblv;
        u32* f       = (u32*)p; p += sz_n4;
        u32* lrank   = (u32*)p; p += sz_n4;
        u32* partials= (u32*)p; p += sz_small;
        u32* pp      = (u32*)p; p += sz_small;
        u32* offsets = (u32*)p;

        argmax_kernel<<<(n + 3) / 4, 256, 0, stream>>>(x, h, out, offsets, n);
        count_part  <<<NBLK, 1024, 0, stream>>>(dst, cnt, m);
        scan_flat   <<<1, 1024, 0, stream>>>(cnt, off);
        scatter_part<<<NBLK, 1024, 0, stream>>>(src, dst, off, packed, m);

        for (int it = 0; it < 3; ++it) {
            nb_kernel    <<<NB + 256, 1024, 0, stream>>>(packed, off, h, nb, keys, vals, n, m);
            sig_kernel   <<<NPB, 256, 0, stream>>>(h, nb, sig, keys, vals, n);
            count_rank   <<<NPB, 256, 0, stream>>>(sig, keys, vals, f, lrank, partials, n);
            scan_partials<<<1, 512, 0, stream>>>(partials, pp, offsets, it, NPB);
            relabel_fast <<<NPB, 256, 0, stream>>>(f, lrank, pp, offsets, it, h, out, n);
        }
    } else {
        // fallback: atomic scatter (round-3 structure)
        u64* h       = (u64*)p; p += sz_h;
        u64* nb      = (u64*)p; p += sz_h;
        u64* sig     = (u64*)p; p += sz_h;
        u64* keys    = (u64*)p; p += sz_tblk;
        u32* vals    = (u32*)p; p += sz_tblv;
        u32* f       = (u32*)p; p += sz_n4;
        u32* lrank   = (u32*)p; p += sz_n4;
        u32* partials= (u32*)p; p += sz_small;
        u32* pp      = (u32*)p; p += sz_small;
        u32* offsets = (u32*)p;

        argmax_kernel<<<(n + 3) / 4, 256, 0, stream>>>(x, h, out, offsets, n);
        for (int it = 0; it < 3; ++it) {
            init_iter_kernel<<<(TBL_SIZE + 255) / 256, 256, 0, stream>>>(keys, vals, nb, n);
            edge_kernel  <<<4096, 256, 0, stream>>>(src, dst, h, nb, m);
            sig_kernel   <<<NPB, 256, 0, stream>>>(h, nb, sig, keys, vals, n);
            count_rank   <<<NPB, 256, 0, stream>>>(sig, keys, vals, f, lrank, partials, n);
            scan_partials<<<1, 512, 0, stream>>>(partials, pp, offsets, it, NPB);
            relabel_fast <<<NPB, 256, 0, stream>>>(f, lrank, pp, offsets, it, h, out, n);
        }
    }
}

// Round 5
// 256.625 us; speedup vs baseline: 5.6245x; 1.2004x over previous
//
#include <hip/hip_runtime.h>

typedef unsigned long long u64;
typedef unsigned int u32;

#define TBL_BITS 18
#define TBL_SIZE (1u << TBL_BITS)
#define TBL_MASK (TBL_SIZE - 1u)
#define EMPTY_KEY 0xFFFFFFFFFFFFFFFFull

#define BK_BITS 7                 // 128-node buckets
#define BK_SZ   128
#define MAXNB   1024              // max buckets supported by fast path
#define NBLK    256               // partition blocks

__device__ __forceinline__ u64 splitmix64(u64 z) {
    z = z + 0x9E3779B97F4A7C15ull;
    z = (z ^ (z >> 30)) * 0xBF58476D1CE4E5B9ull;
    z = (z ^ (z >> 27)) * 0x94D049BB133111EBull;
    return z ^ (z >> 31);
}

// colors0 = argmax over 64 features per node (one wave per row); writes output
// column 0, h = splitmix64(color+1), and offsets[0] = 0.
__global__ void argmax_kernel(const float* __restrict__ x, u64* __restrict__ h,
                              int* __restrict__ out, u32* __restrict__ offsets, int n) {
    if (blockIdx.x == 0 && threadIdx.x == 0) offsets[0] = 0u;
    int wave = (int)((blockIdx.x * (u32)blockDim.x + threadIdx.x) >> 6);
    int lane = threadIdx.x & 63;
    if (wave >= n) return;
    float v = x[(size_t)wave * 64 + lane];
    int idx = lane;
    #pragma unroll
    for (int off = 32; off >= 1; off >>= 1) {
        float ov = __shfl_xor(v, off);
        int   oi = __shfl_xor(idx, off);
        if (ov > v || (ov == v && oi < idx)) { v = ov; idx = oi; }
    }
    if (lane == 0) {
        h[wave] = splitmix64((u64)idx + 1ull);
        out[(size_t)wave * 4 + 0] = idx;
    }
}

// ---------------- fast path: one-time edge partition ----------------

// Per-block LDS histogram of dst buckets -> cnt[bucket*NBLK + blk]. int4 loads.
__global__ __launch_bounds__(1024) void count_part(const int* __restrict__ dst,
                                                   u32* __restrict__ cnt, int m, int nbuck) {
    __shared__ u32 hist[MAXNB];
    int t = threadIdx.x, b = blockIdx.x;
    for (int i = t; i < nbuck; i += 1024) hist[i] = 0u;
    __syncthreads();
    int mv = m >> 2;
    int perv = (mv + NBLK - 1) / NBLK;
    int lo = b * perv, hi = lo + perv; if (hi > mv) hi = mv;
    const int4* d4 = (const int4*)dst;
    for (int i = lo + t; i < hi; i += 1024) {
        int4 v = d4[i];
        atomicAdd(&hist[((u32)v.x) >> BK_BITS], 1u);
        atomicAdd(&hist[((u32)v.y) >> BK_BITS], 1u);
        atomicAdd(&hist[((u32)v.z) >> BK_BITS], 1u);
        atomicAdd(&hist[((u32)v.w) >> BK_BITS], 1u);
    }
    if (b == 0 && t == 0)
        for (int e = mv * 4; e < m; ++e) atomicAdd(&hist[((u32)dst[e]) >> BK_BITS], 1u);
    __syncthreads();
    for (int i = t; i < nbuck; i += 1024) cnt[i * NBLK + b] = hist[i];
}

// In-place exclusive scan of each bucket's NBLK counters; emit bucket totals.
__global__ void scan_bucket(u32* __restrict__ cnt, u32* __restrict__ total, int nbuck) {
    int b = blockIdx.x, t = threadIdx.x;          // 256 threads == NBLK
    u32 v = cnt[b * NBLK + t];
    int lane = t & 63, w = t >> 6;
    int x = (int)v;
    #pragma unroll
    for (int o = 1; o < 64; o <<= 1) {
        int y = __shfl_up(x, o);
        if (lane >= o) x += y;
    }
    __shared__ u32 ws[4];
    if (lane == 63) ws[w] = (u32)x;
    __syncthreads();
    u32 woff = 0;
    for (int ww = 0; ww < w; ++ww) woff += ws[ww];
    u32 incl = woff + (u32)x;
    cnt[b * NBLK + t] = incl - v;                 // exclusive, in place
    if (t == 255) total[b] = incl;
}

// Exclusive scan of bucket totals (padded to 64 -> uint4-aligned regions).
__global__ __launch_bounds__(1024) void scan_bases(const u32* __restrict__ total,
                                                   u32* __restrict__ bases, int nbuck) {
    __shared__ u32 A[1024], B[1024];
    int t = threadIdx.x;
    u32 pt = (t < nbuck) ? ((total[t] + 63u) & ~63u) : 0u;
    A[t] = pt; __syncthreads();
    u32 *cur = A, *nxt = B;
    for (int o = 1; o < 1024; o <<= 1) {
        u32 y = cur[t] + ((t >= o) ? cur[t - o] : 0u);
        nxt[t] = y; __syncthreads();
        u32* tmp = cur; cur = nxt; nxt = tmp;
    }
    if (t < nbuck) bases[t] = cur[t] - pt;
}

// Scatter edges into bucket regions: packed = (src<<7)|(dst&127). Position
// order within a region is nondeterministic, but downstream sums are
// commutative -> final output exact/deterministic.
__global__ __launch_bounds__(1024) void scatter_part(const int* __restrict__ src,
                                                     const int* __restrict__ dst,
                                                     const u32* __restrict__ cnt,
                                                     const u32* __restrict__ bases,
                                                     u32* __restrict__ packed, int m, int nbuck) {
    __shared__ u32 pos[MAXNB];
    int t = threadIdx.x, b = blockIdx.x;
    for (int i = t; i < nbuck; i += 1024) pos[i] = bases[i] + cnt[i * NBLK + b];
    __syncthreads();
    int mv = m >> 2;
    int perv = (mv + NBLK - 1) / NBLK;
    int lo = b * perv, hi = lo + perv; if (hi > mv) hi = mv;
    const int4* d4 = (const int4*)dst;
    const int4* s4 = (const int4*)src;
    for (int i = lo + t; i < hi; i += 1024) {
        int4 dv = d4[i]; int4 sv = s4[i];
        u32 d0 = (u32)dv.x, d1 = (u32)dv.y, d2 = (u32)dv.z, d3 = (u32)dv.w;
        u32 p0 = atomicAdd(&pos[d0 >> BK_BITS], 1u);
        packed[p0] = ((u32)sv.x << BK_BITS) | (d0 & (BK_SZ - 1u));
        u32 p1 = atomicAdd(&pos[d1 >> BK_BITS], 1u);
        packed[p1] = ((u32)sv.y << BK_BITS) | (d1 & (BK_SZ - 1u));
        u32 p2 = atomicAdd(&pos[d2 >> BK_BITS], 1u);
        packed[p2] = ((u32)sv.z << BK_BITS) | (d2 & (BK_SZ - 1u));
        u32 p3 = atomicAdd(&pos[d3 >> BK_BITS], 1u);
        packed[p3] = ((u32)sv.w << BK_BITS) | (d3 & (BK_SZ - 1u));
    }
    if (b == 0 && t == 0) {
        for (int e = mv * 4; e < m; ++e) {
            u32 d = (u32)dst[e];
            u32 p = atomicAdd(&pos[d >> BK_BITS], 1u);
            packed[p] = ((u32)src[e] << BK_BITS) | (d & (BK_SZ - 1u));
        }
    }
}

// Blocks [0,nbuck): bucketed neighbor-sum into 128 u64 LDS accumulators,
// coalesced store. Blocks [nbuck, nbuck+256): clear the hash table.
__global__ __launch_bounds__(256) void nb_kernel(const u32* __restrict__ packed,
                                                 const u32* __restrict__ bases,
                                                 const u32* __restrict__ total,
                                                 const u64* __restrict__ h,
                                                 u64* __restrict__ nb,
                                                 u64* __restrict__ keys,
                                                 u32* __restrict__ vals, int n, int nbuck) {
    int b = blockIdx.x, t = threadIdx.x;
    if (b >= nbuck) {
        int base = (b - nbuck) * 1024;
        for (int k = t; k < 1024; k += 256) { keys[base + k] = EMPTY_KEY; vals[base + k] = 0xFFFFFFFFu; }
        return;
    }
    __shared__ u64 acc[BK_SZ];
    if (t < BK_SZ) acc[t] = 0ull;
    __syncthreads();
    u32 lo = bases[b];           // multiple of 64 -> uint4 aligned
    u32 len = total[b];
    const uint4* p4 = (const uint4*)(packed + lo);
    int len4 = (int)(len >> 2);
    for (int i = t; i < len4; i += 256) {
        uint4 v = p4[i];
        atomicAdd(&acc[v.x & (BK_SZ - 1u)], h[v.x >> BK_BITS]);
        atomicAdd(&acc[v.y & (BK_SZ - 1u)], h[v.y >> BK_BITS]);
        atomicAdd(&acc[v.z & (BK_SZ - 1u)], h[v.z >> BK_BITS]);
        atomicAdd(&acc[v.w & (BK_SZ - 1u)], h[v.w >> BK_BITS]);
    }
    for (int e = len4 * 4 + t; e < (int)len; e += 256) {
        u32 v = packed[lo + e];
        atomicAdd(&acc[v & (BK_SZ - 1u)], h[v >> BK_BITS]);
    }
    __syncthreads();
    if (t < BK_SZ) {
        int node = (b << BK_BITS) + t;
        if (node < n) nb[node] = acc[t];
    }
}

// ---------------- per-iteration relabel chain ----------------

// sig = splitmix64(h*FNV + nb); insert into table; record slot per node;
// first occurrence via atomicMin (order-independent).
__global__ void sig_kernel(const u64* __restrict__ h, const u64* __restrict__ nb,
                           u32* __restrict__ slotarr, u64* __restrict__ keys,
                           u32* __restrict__ vals, int n) {
    int i = blockIdx.x * blockDim.x + threadIdx.x;
    if (i >= n) return;
    u64 s = splitmix64(h[i] * 0x100000001B3ull + nb[i]);
    u32 slot = (u32)s & TBL_MASK;
    while (true) {
        u64 prev = atomicCAS(&keys[slot], (u64)EMPTY_KEY, s);
        if (prev == EMPTY_KEY || prev == s) break;
        slot = (slot + 1u) & TBL_MASK;
    }
    atomicMin(&vals[slot], (u32)i);
    slotarr[i] = slot;
}

// f[i] = first-occurrence index; per-block exclusive rank of is-first; totals.
__global__ void count_rank(const u32* __restrict__ slotarr, const u32* __restrict__ vals,
                           u32* __restrict__ f, u32* __restrict__ lrank,
                           u32* __restrict__ partials, int n) {
    int b = blockIdx.x, t = threadIdx.x;
    int i = b * 256 + t;
    u32 isf = 0, fi = 0;
    if (i < n) {
        fi = vals[slotarr[i]];
        f[i] = fi;
        isf = (fi == (u32)i) ? 1u : 0u;
    }
    __shared__ u32 wsum[4];
    u32 lane = t & 63, wv = (u32)t >> 6;
    int x = (int)isf;
    #pragma unroll
    for (int o = 1; o < 64; o <<= 1) {
        int y = __shfl_up(x, o);
        if (lane >= (u32)o) x += y;
    }
    if (lane == 63) wsum[wv] = (u32)x;
    __syncthreads();
    u32 woff = 0;
    for (u32 w = 0; w < wv; ++w) woff += wsum[w];
    if (i < n) lrank[i] = woff + (u32)x - isf;
    if (t == 255) partials[b] = woff + (u32)x;
}

// Exclusive scan of per-block totals; advance the color counter.
__global__ void scan_partials(const u32* __restrict__ partials, u32* __restrict__ pp,
                              u32* __restrict__ offsets, int iter, int nblk) {
    __shared__ u32 A[512], B[512];
    int t = threadIdx.x;
    u32 v = (t < nblk) ? partials[t] : 0u;
    A[t] = v; __syncthreads();
    u32 *cur = A, *nxt = B;
    for (int o = 1; o < 512; o <<= 1) {
        u32 y = cur[t] + ((t >= o) ? cur[t - o] : 0u);
        nxt[t] = y; __syncthreads();
        u32* tmp = cur; cur = nxt; nxt = tmp;
    }
    if (t < nblk) pp[t] = cur[t] - v;
    if (t == 511) offsets[iter + 1] = offsets[iter] + cur[511];
}

// color = offset + global rank of first occurrence; emit column + next h.
__global__ void relabel_fast(const u32* __restrict__ f, const u32* __restrict__ lrank,
                             const u32* __restrict__ pp, const u32* __restrict__ offsets,
                             int iter, u64* __restrict__ h, int* __restrict__ out, int n) {
    int i = blockIdx.x * 256 + threadIdx.x;
    if (i >= n) return;
    u32 j = f[i];
    u32 c = offsets[iter] + pp[j >> 8] + lrank[j];
    h[i] = splitmix64((u64)c + 1ull);
    out[(size_t)i * 4 + (iter + 1)] = (int)c;
}

// ---------------- fallback path (proven) ----------------

__global__ void init_iter_kernel(u64* __restrict__ keys, u32* __restrict__ vals,
                                 u64* __restrict__ nb, int n) {
    int i = blockIdx.x * blockDim.x + threadIdx.x;
    if (i < (int)TBL_SIZE) { keys[i] = EMPTY_KEY; vals[i] = 0xFFFFFFFFu; }
    if (i < n) nb[i] = 0ull;
}

__global__ void edge_kernel(const int* __restrict__ src, const int* __restrict__ dst,
                            const u64* __restrict__ h, u64* __restrict__ nb, int m) {
    int stride = gridDim.x * blockDim.x;
    for (int e = blockIdx.x * blockDim.x + threadIdx.x; e < m; e += stride) {
        atomicAdd(&nb[(u32)dst[e]], h[(u32)src[e]]);
    }
}

extern "C" void kernel_launch(void* const* d_in, const int* in_sizes, int n_in,
                              void* d_out, int out_size, void* d_ws, size_t ws_size,
                              hipStream_t stream) {
    const float* x = (const float*)d_in[0];
    const int* ei = (const int*)d_in[1];     // int32 on device
    int n = in_sizes[0] / 64;
    int m = in_sizes[1] / 2;
    const int* src = ei;
    const int* dst = ei + m;
    int* out = (int*)d_out;

    const int NPB = (n + 255) / 256;
    const int nbuck = (n + BK_SZ - 1) >> BK_BITS;

    auto align = [](size_t v) { return (v + 255) & ~(size_t)255; };
    size_t sz_packed = align((size_t)m * 4 + (size_t)MAXNB * 64 * 4);
    size_t sz_cnt    = align((size_t)MAXNB * NBLK * 4);
    size_t sz_bt     = align((size_t)MAXNB * 4);
    size_t sz_h      = align((size_t)n * 8);
    size_t sz_tblk   = align((size_t)TBL_SIZE * 8);
    size_t sz_tblv   = align((size_t)TBL_SIZE * 4);
    size_t sz_n4     = align((size_t)n * 4);
    size_t sz_small  = align((size_t)512 * 4);
    size_t need_fast = sz_packed + sz_cnt + 2 * sz_bt + 2 * sz_h + sz_tblk + sz_tblv
                     + 3 * sz_n4 + 2 * sz_small + 256;

    char* p = (char*)d_ws;
    bool fast = (ws_size >= need_fast) && (nbuck <= MAXNB) && ((m & 3) == 0) && (NPB <= 512);
    if (fast) {
        u32* packed  = (u32*)p; p += sz_packed;
        u32* cnt     = (u32*)p; p += sz_cnt;
        u32* total   = (u32*)p; p += sz_bt;
        u32* bases   = (u32*)p; p += sz_bt;
        u64* h       = (u64*)p; p += sz_h;
        u64* nb      = (u64*)p; p += sz_h;
        u64* keys    = (u64*)p; p += sz_tblk;
        u32* vals    = (u32*)p; p += sz_tblv;
        u32* slotarr = (u32*)p; p += sz_n4;
        u32* f       = (u32*)p; p += sz_n4;
        u32* lrank   = (u32*)p; p += sz_n4;
        u32* partials= (u32*)p; p += sz_small;
        u32* pp      = (u32*)p; p += sz_small;
        u32* offsets = (u32*)p;

        argmax_kernel<<<(n + 3) / 4, 256, 0, stream>>>(x, h, out, offsets, n);
        count_part  <<<NBLK, 1024, 0, stream>>>(dst, cnt, m, nbuck);
        scan_bucket <<<nbuck, 256, 0, stream>>>(cnt, total, nbuck);
        scan_bases  <<<1, 1024, 0, stream>>>(total, bases, nbuck);
        scatter_part<<<NBLK, 1024, 0, stream>>>(src, dst, cnt, bases, packed, m, nbuck);

        for (int it = 0; it < 3; ++it) {
            nb_kernel    <<<nbuck + 256, 256, 0, stream>>>(packed, bases, total, h, nb, keys, vals, n, nbuck);
            sig_kernel   <<<NPB, 256, 0, stream>>>(h, nb, slotarr, keys, vals, n);
            count_rank   <<<NPB, 256, 0, stream>>>(slotarr, vals, f, lrank, partials, n);
            scan_partials<<<1, 512, 0, stream>>>(partials, pp, offsets, it, NPB);
            relabel_fast <<<NPB, 256, 0, stream>>>(f, lrank, pp, offsets, it, h, out, n);
        }
    } else {
        u64* h       = (u64*)p; p += sz_h;
        u64* nb      = (u64*)p; p += sz_h;
        u64* keys    = (u64*)p; p += sz_tblk;
        u32* vals    = (u32*)p; p += sz_tblv;
        u32* slotarr = (u32*)p; p += sz_n4;
        u32* f       = (u32*)p; p += sz_n4;
        u32* lrank   = (u32*)p; p += sz_n4;
        u32* partials= (u32*)p; p += sz_small;
        u32* pp      = (u32*)p; p += sz_small;
        u32* offsets = (u32*)p;

        argmax_kernel<<<(n + 3) / 4, 256, 0, stream>>>(x, h, out, offsets, n);
        for (int it = 0; it < 3; ++it) {
            init_iter_kernel<<<(TBL_SIZE + 255) / 256, 256, 0, stream>>>(keys, vals, nb, n);
            edge_kernel  <<<4096, 256, 0, stream>>>(src, dst, h, nb, m);
            sig_kernel   <<<NPB, 256, 0, stream>>>(h, nb, slotarr, keys, vals, n);
            count_rank   <<<NPB, 256, 0, stream>>>(slotarr, vals, f, lrank, partials, n);
            scan_partials<<<1, 512, 0, stream>>>(partials, pp, offsets, it, NPB);
            relabel_fast <<<NPB, 256, 0, stream>>>(f, lrank, pp, offsets, it, h, out, n);
        }
    }
}

// Round 6
// 251.568 us; speedup vs baseline: 5.7376x; 1.0201x over previous
//
#include <hip/hip_runtime.h>

typedef unsigned long long u64;
typedef unsigned int u32;

#define TBL_BITS 18
#define TBL_SIZE (1u << TBL_BITS)
#define TBL_MASK (TBL_SIZE - 1u)
#define EMPTY_KEY 0xFFFFFFFFFFFFFFFFull

#define BK_BITS 9                 // 512-node buckets
#define BK_SZ   512
#define MAXNB   256               // max coarse buckets in fast path
#define NBLK    256               // partition blocks
#define NSUB    4                 // nb sub-blocks per bucket

__device__ __forceinline__ u64 splitmix64(u64 z) {
    z = z + 0x9E3779B97F4A7C15ull;
    z = (z ^ (z >> 30)) * 0xBF58476D1CE4E5B9ull;
    z = (z ^ (z >> 27)) * 0x94D049BB133111EBull;
    return z ^ (z >> 31);
}

// colors0 = argmax over 64 features per node (one wave per row); writes output
// column 0, h = splitmix64(color+1), and offsets[0] = 0.
__global__ void argmax_kernel(const float* __restrict__ x, u64* __restrict__ h,
                              int* __restrict__ out, u32* __restrict__ offsets, int n) {
    if (blockIdx.x == 0 && threadIdx.x == 0) offsets[0] = 0u;
    int wave = (int)((blockIdx.x * (u32)blockDim.x + threadIdx.x) >> 6);
    int lane = threadIdx.x & 63;
    if (wave >= n) return;
    float v = x[(size_t)wave * 64 + lane];
    int idx = lane;
    #pragma unroll
    for (int off = 32; off >= 1; off >>= 1) {
        float ov = __shfl_xor(v, off);
        int   oi = __shfl_xor(idx, off);
        if (ov > v || (ov == v && oi < idx)) { v = ov; idx = oi; }
    }
    if (lane == 0) {
        h[wave] = splitmix64((u64)idx + 1ull);
        out[(size_t)wave * 4 + 0] = idx;
    }
}

// ---------------- fast path: one-time edge partition ----------------

// Per-block LDS histogram of dst buckets -> cnt[bucket*NBLK + blk]. int4 loads.
__global__ __launch_bounds__(1024) void count_part(const int* __restrict__ dst,
                                                   u32* __restrict__ cnt, int m, int nbuck) {
    __shared__ u32 hist[MAXNB];
    int t = threadIdx.x, b = blockIdx.x;
    for (int i = t; i < nbuck; i += 1024) hist[i] = 0u;
    __syncthreads();
    int mv = m >> 2;
    int perv = (mv + NBLK - 1) / NBLK;
    int lo = b * perv, hi = lo + perv; if (hi > mv) hi = mv;
    const int4* d4 = (const int4*)dst;
    for (int i = lo + t; i < hi; i += 1024) {
        int4 v = d4[i];
        atomicAdd(&hist[((u32)v.x) >> BK_BITS], 1u);
        atomicAdd(&hist[((u32)v.y) >> BK_BITS], 1u);
        atomicAdd(&hist[((u32)v.z) >> BK_BITS], 1u);
        atomicAdd(&hist[((u32)v.w) >> BK_BITS], 1u);
    }
    if (b == 0 && t == 0)
        for (int e = mv * 4; e < m; ++e) atomicAdd(&hist[((u32)dst[e]) >> BK_BITS], 1u);
    __syncthreads();
    for (int i = t; i < nbuck; i += 1024) cnt[i * NBLK + b] = hist[i];
}

// In-place exclusive scan of each bucket's NBLK counters; emit bucket totals.
__global__ void scan_bucket(u32* __restrict__ cnt, u32* __restrict__ total, int nbuck) {
    int b = blockIdx.x, t = threadIdx.x;          // 256 threads == NBLK
    u32 v = cnt[b * NBLK + t];
    int lane = t & 63, w = t >> 6;
    int x = (int)v;
    #pragma unroll
    for (int o = 1; o < 64; o <<= 1) {
        int y = __shfl_up(x, o);
        if (lane >= o) x += y;
    }
    __shared__ u32 ws[4];
    if (lane == 63) ws[w] = (u32)x;
    __syncthreads();
    u32 woff = 0;
    for (int ww = 0; ww < w; ++ww) woff += ws[ww];
    u32 incl = woff + (u32)x;
    cnt[b * NBLK + t] = incl - v;                 // exclusive, in place
    if (t == 255) total[b] = incl;
}

// Exclusive scan of bucket totals (padded to 64-entry alignment).
__global__ void scan_bases(const u32* __restrict__ total, u32* __restrict__ bases, int nbuck) {
    __shared__ u32 A[256], B[256];
    int t = threadIdx.x;
    u32 pt = (t < nbuck) ? ((total[t] + 63u) & ~63u) : 0u;
    A[t] = pt; __syncthreads();
    u32 *cur = A, *nxt = B;
    for (int o = 1; o < 256; o <<= 1) {
        u32 y = cur[t] + ((t >= o) ? cur[t - o] : 0u);
        nxt[t] = y; __syncthreads();
        u32* tmp = cur; cur = nxt; nxt = tmp;
    }
    if (t < nbuck) bases[t] = cur[t] - pt;
}

// Scatter edges into bucket regions: packed = (src<<9)|(dst&511). Position
// order within a region is nondeterministic, but downstream sums are
// commutative -> final output exact/deterministic.
__global__ __launch_bounds__(1024) void scatter_part(const int* __restrict__ src,
                                                     const int* __restrict__ dst,
                                                     const u32* __restrict__ cnt,
                                                     const u32* __restrict__ bases,
                                                     u32* __restrict__ packed, int m, int nbuck) {
    __shared__ u32 pos[MAXNB];
    int t = threadIdx.x, b = blockIdx.x;
    for (int i = t; i < nbuck; i += 1024) pos[i] = bases[i] + cnt[i * NBLK + b];
    __syncthreads();
    int mv = m >> 2;
    int perv = (mv + NBLK - 1) / NBLK;
    int lo = b * perv, hi = lo + perv; if (hi > mv) hi = mv;
    const int4* d4 = (const int4*)dst;
    const int4* s4 = (const int4*)src;
    for (int i = lo + t; i < hi; i += 1024) {
        int4 dv = d4[i]; int4 sv = s4[i];
        u32 d0 = (u32)dv.x, d1 = (u32)dv.y, d2 = (u32)dv.z, d3 = (u32)dv.w;
        u32 p0 = atomicAdd(&pos[d0 >> BK_BITS], 1u);
        packed[p0] = ((u32)sv.x << BK_BITS) | (d0 & (BK_SZ - 1u));
        u32 p1 = atomicAdd(&pos[d1 >> BK_BITS], 1u);
        packed[p1] = ((u32)sv.y << BK_BITS) | (d1 & (BK_SZ - 1u));
        u32 p2 = atomicAdd(&pos[d2 >> BK_BITS], 1u);
        packed[p2] = ((u32)sv.z << BK_BITS) | (d2 & (BK_SZ - 1u));
        u32 p3 = atomicAdd(&pos[d3 >> BK_BITS], 1u);
        packed[p3] = ((u32)sv.w << BK_BITS) | (d3 & (BK_SZ - 1u));
    }
    if (b == 0 && t == 0) {
        for (int e = mv * 4; e < m; ++e) {
            u32 d = (u32)dst[e];
            u32 p = atomicAdd(&pos[d >> BK_BITS], 1u);
            packed[p] = ((u32)src[e] << BK_BITS) | (d & (BK_SZ - 1u));
        }
    }
}

// Blocks [0, nbuck*NSUB): sub-block s of bucket b accumulates its quarter of
// the bucket's edges into 512 u64 LDS accumulators, then OVERWRITES its slice
// of partial array nb4[s] (no global atomics, no pre-clear needed).
// Blocks [nbuck*NSUB, +256): clear the hash table.
__global__ __launch_bounds__(256) void nb_kernel(const u32* __restrict__ packed,
                                                 const u32* __restrict__ bases,
                                                 const u32* __restrict__ total,
                                                 const u64* __restrict__ h,
                                                 u64* __restrict__ nb4, size_t nstride,
                                                 u64* __restrict__ keys,
                                                 u32* __restrict__ vals, int nbuck) {
    int b = blockIdx.x, t = threadIdx.x;
    if (b >= nbuck * NSUB) {
        int base = (b - nbuck * NSUB) * 1024;
        for (int k = t; k < 1024; k += 256) { keys[base + k] = EMPTY_KEY; vals[base + k] = 0xFFFFFFFFu; }
        return;
    }
    int bucket = b >> 2, sub = b & 3;
    __shared__ u64 acc[BK_SZ];
    acc[t] = 0ull; acc[t + 256] = 0ull;
    __syncthreads();
    u32 lo = bases[bucket];
    u32 len = total[bucket];
    u32 q0 = (len * (u32)sub) >> 2;
    u32 q1 = (len * (u32)(sub + 1)) >> 2;
    for (u32 e = lo + q0 + (u32)t; e < lo + q1; e += 256) {
        u32 v = packed[e];
        atomicAdd(&acc[v & (BK_SZ - 1u)], h[v >> BK_BITS]);
    }
    __syncthreads();
    u64* dst = nb4 + (size_t)sub * nstride + ((size_t)bucket << BK_BITS);
    dst[t] = acc[t];
    dst[t + 256] = acc[t + 256];
}

// ---------------- per-iteration relabel chain ----------------

// sig = splitmix64(h*FNV + sum of 4 nb partials); read-before-CAS insert;
// first occurrence via atomicMin (order-independent). Slots are write-once
// EMPTY->key, so a stale plain read yields EMPTY or the final key -> safe.
__global__ void sig_kernel4(const u64* __restrict__ h, const u64* __restrict__ nb4,
                            size_t nstride, u32* __restrict__ slotarr,
                            u64* __restrict__ keys, u32* __restrict__ vals, int n) {
    int i = blockIdx.x * blockDim.x + threadIdx.x;
    if (i >= n) return;
    u64 nbv = nb4[i] + nb4[nstride + i] + nb4[2 * nstride + i] + nb4[3 * nstride + i];
    u64 s = splitmix64(h[i] * 0x100000001B3ull + nbv);
    u32 slot = (u32)s & TBL_MASK;
    while (true) {
        u64 k = keys[slot];
        if (k == s) break;
        if (k == EMPTY_KEY) {
            u64 prev = atomicCAS(&keys[slot], (u64)EMPTY_KEY, s);
            if (prev == EMPTY_KEY || prev == s) break;
        }
        slot = (slot + 1u) & TBL_MASK;
    }
    atomicMin(&vals[slot], (u32)i);
    slotarr[i] = slot;
}

__global__ void sig_kernel1(const u64* __restrict__ h, const u64* __restrict__ nb,
                            u32* __restrict__ slotarr, u64* __restrict__ keys,
                            u32* __restrict__ vals, int n) {
    int i = blockIdx.x * blockDim.x + threadIdx.x;
    if (i >= n) return;
    u64 s = splitmix64(h[i] * 0x100000001B3ull + nb[i]);
    u32 slot = (u32)s & TBL_MASK;
    while (true) {
        u64 k = keys[slot];
        if (k == s) break;
        if (k == EMPTY_KEY) {
            u64 prev = atomicCAS(&keys[slot], (u64)EMPTY_KEY, s);
            if (prev == EMPTY_KEY || prev == s) break;
        }
        slot = (slot + 1u) & TBL_MASK;
    }
    atomicMin(&vals[slot], (u32)i);
    slotarr[i] = slot;
}

// f[i] = first-occurrence index; per-block exclusive rank of is-first; totals.
__global__ void count_rank(const u32* __restrict__ slotarr, const u32* __restrict__ vals,
                           u32* __restrict__ f, u32* __restrict__ lrank,
                           u32* __restrict__ partials, int n) {
    int b = blockIdx.x, t = threadIdx.x;
    int i = b * 256 + t;
    u32 isf = 0, fi = 0;
    if (i < n) {
        fi = vals[slotarr[i]];
        f[i] = fi;
        isf = (fi == (u32)i) ? 1u : 0u;
    }
    __shared__ u32 wsum[4];
    u32 lane = t & 63, wv = (u32)t >> 6;
    int x = (int)isf;
    #pragma unroll
    for (int o = 1; o < 64; o <<= 1) {
        int y = __shfl_up(x, o);
        if (lane >= (u32)o) x += y;
    }
    if (lane == 63) wsum[wv] = (u32)x;
    __syncthreads();
    u32 woff = 0;
    for (u32 w = 0; w < wv; ++w) woff += wsum[w];
    if (i < n) lrank[i] = woff + (u32)x - isf;
    if (t == 255) partials[b] = woff + (u32)x;
}

// Exclusive scan of per-block totals; advance the color counter.
__global__ void scan_partials(const u32* __restrict__ partials, u32* __restrict__ pp,
                              u32* __restrict__ offsets, int iter, int nblk) {
    __shared__ u32 A[512], B[512];
    int t = threadIdx.x;
    u32 v = (t < nblk) ? partials[t] : 0u;
    A[t] = v; __syncthreads();
    u32 *cur = A, *nxt = B;
    for (int o = 1; o < 512; o <<= 1) {
        u32 y = cur[t] + ((t >= o) ? cur[t - o] : 0u);
        nxt[t] = y; __syncthreads();
        u32* tmp = cur; cur = nxt; nxt = tmp;
    }
    if (t < nblk) pp[t] = cur[t] - v;
    if (t == 511) offsets[iter + 1] = offsets[iter] + cur[511];
}

// color = offset + global rank of first occurrence; emit column + next h.
__global__ void relabel_fast(const u32* __restrict__ f, const u32* __restrict__ lrank,
                             const u32* __restrict__ pp, const u32* __restrict__ offsets,
                             int iter, u64* __restrict__ h, int* __restrict__ out, int n) {
    int i = blockIdx.x * 256 + threadIdx.x;
    if (i >= n) return;
    u32 j = f[i];
    u32 c = offsets[iter] + pp[j >> 8] + lrank[j];
    h[i] = splitmix64((u64)c + 1ull);
    out[(size_t)i * 4 + (iter + 1)] = (int)c;
}

// ---------------- fallback path (proven) ----------------

__global__ void init_iter_kernel(u64* __restrict__ keys, u32* __restrict__ vals,
                                 u64* __restrict__ nb, int n) {
    int i = blockIdx.x * blockDim.x + threadIdx.x;
    if (i < (int)TBL_SIZE) { keys[i] = EMPTY_KEY; vals[i] = 0xFFFFFFFFu; }
    if (i < n) nb[i] = 0ull;
}

__global__ void edge_kernel(const int* __restrict__ src, const int* __restrict__ dst,
                            const u64* __restrict__ h, u64* __restrict__ nb, int m) {
    int stride = gridDim.x * blockDim.x;
    for (int e = blockIdx.x * blockDim.x + threadIdx.x; e < m; e += stride) {
        atomicAdd(&nb[(u32)dst[e]], h[(u32)src[e]]);
    }
}

extern "C" void kernel_launch(void* const* d_in, const int* in_sizes, int n_in,
                              void* d_out, int out_size, void* d_ws, size_t ws_size,
                              hipStream_t stream) {
    const float* x = (const float*)d_in[0];
    const int* ei = (const int*)d_in[1];     // int32 on device
    int n = in_sizes[0] / 64;
    int m = in_sizes[1] / 2;
    const int* src = ei;
    const int* dst = ei + m;
    int* out = (int*)d_out;

    const int NPB = (n + 255) / 256;
    const int nbuck = (n + BK_SZ - 1) >> BK_BITS;
    const size_t nstride = (size_t)nbuck << BK_BITS;   // padded node count

    auto align = [](size_t v) { return (v + 255) & ~(size_t)255; };
    size_t sz_packed = align((size_t)m * 4 + (size_t)MAXNB * 64 * 4);
    size_t sz_cnt    = align((size_t)MAXNB * NBLK * 4);
    size_t sz_bt     = align((size_t)MAXNB * 4);
    size_t sz_h      = align((size_t)n * 8);
    size_t sz_nb4    = align(nstride * 8 * NSUB);
    size_t sz_tblk   = align((size_t)TBL_SIZE * 8);
    size_t sz_tblv   = align((size_t)TBL_SIZE * 4);
    size_t sz_n4     = align((size_t)n * 4);
    size_t sz_small  = align((size_t)512 * 4);
    size_t need_fast = sz_packed + sz_cnt + 2 * sz_bt + sz_h + sz_nb4 + sz_tblk + sz_tblv
                     + 3 * sz_n4 + 2 * sz_small + 256;

    char* p = (char*)d_ws;
    bool fast = (ws_size >= need_fast) && (nbuck <= MAXNB) && ((m & 3) == 0) && (NPB <= 512);
    if (fast) {
        u32* packed  = (u32*)p; p += sz_packed;
        u32* cnt     = (u32*)p; p += sz_cnt;
        u32* total   = (u32*)p; p += sz_bt;
        u32* bases   = (u32*)p; p += sz_bt;
        u64* h       = (u64*)p; p += sz_h;
        u64* nb4     = (u64*)p; p += sz_nb4;
        u64* keys    = (u64*)p; p += sz_tblk;
        u32* vals    = (u32*)p; p += sz_tblv;
        u32* slotarr = (u32*)p; p += sz_n4;
        u32* f       = (u32*)p; p += sz_n4;
        u32* lrank   = (u32*)p; p += sz_n4;
        u32* partials= (u32*)p; p += sz_small;
        u32* pp      = (u32*)p; p += sz_small;
        u32* offsets = (u32*)p;

        argmax_kernel<<<(n + 3) / 4, 256, 0, stream>>>(x, h, out, offsets, n);
        count_part  <<<NBLK, 1024, 0, stream>>>(dst, cnt, m, nbuck);
        scan_bucket <<<nbuck, 256, 0, stream>>>(cnt, total, nbuck);
        scan_bases  <<<1, 256, 0, stream>>>(total, bases, nbuck);
        scatter_part<<<NBLK, 1024, 0, stream>>>(src, dst, cnt, bases, packed, m, nbuck);

        for (int it = 0; it < 3; ++it) {
            nb_kernel    <<<nbuck * NSUB + 256, 256, 0, stream>>>(packed, bases, total, h,
                                                                  nb4, nstride, keys, vals, nbuck);
            sig_kernel4  <<<NPB, 256, 0, stream>>>(h, nb4, nstride, slotarr, keys, vals, n);
            count_rank   <<<NPB, 256, 0, stream>>>(slotarr, vals, f, lrank, partials, n);
            scan_partials<<<1, 512, 0, stream>>>(partials, pp, offsets, it, NPB);
            relabel_fast <<<NPB, 256, 0, stream>>>(f, lrank, pp, offsets, it, h, out, n);
        }
    } else {
        u64* h       = (u64*)p; p += sz_h;
        u64* nb      = (u64*)p; p += sz_h;
        u64* keys    = (u64*)p; p += sz_tblk;
        u32* vals    = (u32*)p; p += sz_tblv;
        u32* slotarr = (u32*)p; p += sz_n4;
        u32* f       = (u32*)p; p += sz_n4;
        u32* lrank   = (u32*)p; p += sz_n4;
        u32* partials= (u32*)p; p += sz_small;
        u32* pp      = (u32*)p; p += sz_small;
        u32* offsets = (u32*)p;

        argmax_kernel<<<(n + 3) / 4, 256, 0, stream>>>(x, h, out, offsets, n);
        for (int it = 0; it < 3; ++it) {
            init_iter_kernel<<<(TBL_SIZE + 255) / 256, 256, 0, stream>>>(keys, vals, nb, n);
            edge_kernel  <<<4096, 256, 0, stream>>>(src, dst, h, nb, m);
            sig_kernel1  <<<NPB, 256, 0, stream>>>(h, nb, slotarr, keys, vals, n);
            count_rank   <<<NPB, 256, 0, stream>>>(slotarr, vals, f, lrank, partials, n);
            scan_partials<<<1, 512, 0, stream>>>(partials, pp, offsets, it, NPB);
            relabel_fast <<<NPB, 256, 0, stream>>>(f, lrank, pp, offsets, it, h, out, n);
        }
    }
}